// Round 1
// baseline (217.474 us; speedup 1.0000x reference)
//
#include <hip/hip_runtime.h>
#include <hip/hip_bf16.h>
#include <math.h>

#define BATCH 512
#define EMBED 512
#define NCLS  100000
#define BM 128
#define BN 128
#define BK 64
#define KT (EMBED/BK)      // 8
#define NCHUNK 782         // ceil(100000/128); padded classes masked
#define NCHUNK2 (NCHUNK*2) // per-wave (64-col) partials per row

typedef __attribute__((ext_vector_type(4))) float f32x4;
typedef __attribute__((ext_vector_type(8))) __bf16 bf16x8;

__device__ __forceinline__ unsigned short f2bf(float f) {
  unsigned int u = __builtin_bit_cast(unsigned int, f);
  u += 0x7fffu + ((u >> 16) & 1u);   // round-to-nearest-even
  return (unsigned short)(u >> 16);
}

constexpr float kCOS_M = 0.8775825618903728f;   // cos(0.5)
constexpr float kSIN_M = 0.4794255386042030f;   // sin(0.5)
constexpr float kTHR   = -0.8775825618903728f;  // cos(pi-0.5)
constexpr float kMM    = 0.2397127693021015f;   // sin(pi-0.5)*0.5
constexpr float kSCALE = 64.0f;
#define NEG_BIG (-1.0e30f)

// ---------------- K1: normalize embeddings -> bf16 ----------------
__global__ void knorm_e(const float* __restrict__ E, unsigned short* __restrict__ En) {
  int row = blockIdx.x;
  int l = threadIdx.x;  // 64 lanes, one wave per row
  const float4* src = (const float4*)(E + row * EMBED);
  float4 a = src[l];
  float4 b = src[l + 64];
  float ss = a.x*a.x + a.y*a.y + a.z*a.z + a.w*a.w
           + b.x*b.x + b.y*b.y + b.z*b.z + b.w*b.w;
#pragma unroll
  for (int d = 1; d < 64; d <<= 1) ss += __shfl_xor(ss, d);
  float rn = 1.0f / fmaxf(sqrtf(ss), 1e-12f);
  ushort4 o;
  o.x = f2bf(a.x * rn); o.y = f2bf(a.y * rn); o.z = f2bf(a.z * rn); o.w = f2bf(a.w * rn);
  ((ushort4*)(En + row * EMBED))[l] = o;
  o.x = f2bf(b.x * rn); o.y = f2bf(b.y * rn); o.z = f2bf(b.z * rn); o.w = f2bf(b.w * rn);
  ((ushort4*)(En + row * EMBED))[l + 64] = o;
}

// ---------------- K2: fused GEMM + margin + partial softmax ----------------
__global__ __launch_bounds__(256, 2) void kgemm(
    const unsigned short* __restrict__ En, const float* __restrict__ W,
    const int* __restrict__ labels,
    float* __restrict__ pmax, float* __restrict__ psum,
    float* __restrict__ lablog)
{
  __shared__ unsigned short Al[2][BM * BK];
  __shared__ unsigned short Bl[2][BN * BK];
  __shared__ float rowsum[BN];
  __shared__ int   lab[BM];

  // XCD-bijective swizzle: 3128 blocks = 8 * 391 exactly; panel fastest so
  // the 4 row-panels sharing one W-tile are adjacent on the same XCD.
  int wg = blockIdx.x;
  wg = (wg & 7) * 391 + (wg >> 3);
  int panel  = wg & 3;
  int cchunk = wg >> 2;
  int row0 = panel * BM;
  int c0   = cchunk * BN;

  int tid = threadIdx.x;
  int w = tid >> 6, lane = tid & 63;
  int wr = w >> 1, wc = w & 1;
  int lr = lane & 15, lg = lane >> 4;

  if (tid < BM) { lab[tid] = labels[row0 + tid]; rowsum[tid] = 0.0f; }
  __syncthreads();

  // A staging: global_load_lds, linear LDS dest, inverse-(XOR)-swizzled source
  auto stageA = [&](int buf, int kt) {
#pragma unroll
    for (int i = 0; i < 4; ++i) {
      int p = ((w * 4 + i) << 10) + (lane << 4);  // byte pos in 16KB tile
      int r = p >> 7;
      int c16 = (p >> 4) & 7;
      int cs = c16 ^ (r & 7);
      const unsigned short* g = En + (row0 + r) * EMBED + kt * BK + cs * 8;
      __builtin_amdgcn_global_load_lds(
          (const __attribute__((address_space(1))) void*)g,
          (__attribute__((address_space(3))) void*)(&Al[buf][(w * 4 + i) * 512]),
          16, 0, 0);
    }
  };

  // B staging: f32 loads (issued early) ...
  auto loadB = [&](int kt, f32x4* bv) {
    bool full = (c0 + BN <= NCLS);
#pragma unroll
    for (int i = 0; i < 8; ++i) {
      int f = i * 256 + tid;
      int r = f >> 4;
      int c4 = f & 15;
      int cg = c0 + r;
      f32x4 v = {0.f, 0.f, 0.f, 0.f};
      if (full || cg < NCLS)
        v = ((const f32x4*)(W + (size_t)cg * EMBED + kt * BK))[c4];
      bv[i] = v;
    }
  };
  // ... cvt+sumsq+swizzled LDS write (after compute)
  auto writeB = [&](int buf, f32x4* bv) {
#pragma unroll
    for (int i = 0; i < 8; ++i) {
      int f = i * 256 + tid;
      int r = f >> 4;
      int c4 = f & 15;
      f32x4 v = bv[i];
      float ss = v.x * v.x + v.y * v.y + v.z * v.z + v.w * v.w;
      ss += __shfl_xor(ss, 1); ss += __shfl_xor(ss, 2);
      ss += __shfl_xor(ss, 4); ss += __shfl_xor(ss, 8);
      if ((tid & 15) == 0) rowsum[r] += ss;  // unique (i,group)->row: race-free
      ushort4 o;
      o.x = f2bf(v.x); o.y = f2bf(v.y); o.z = f2bf(v.z); o.w = f2bf(v.w);
      int boff = r * 128 + ((c4 * 8) ^ ((r & 7) << 4));
      *(ushort4*)((char*)&Bl[buf][0] + boff) = o;
    }
  };

  f32x4 acc[4][4];
#pragma unroll
  for (int m = 0; m < 4; ++m)
#pragma unroll
    for (int n = 0; n < 4; ++n) acc[m][n] = (f32x4){0.f, 0.f, 0.f, 0.f};

  // prologue: tile 0
  stageA(0, 0);
  { f32x4 bv[8]; loadB(0, bv); writeB(0, bv); }
  __syncthreads();

  for (int t = 0; t < KT; ++t) {
    int cur = t & 1;
    f32x4 bv[8];
    if (t + 1 < KT) {
      stageA(cur ^ 1, t + 1);   // async -> other buffer
      loadB(t + 1, bv);         // issue early, consume after MFMA
    }
#pragma unroll
    for (int kk = 0; kk < 2; ++kk) {
      bf16x8 af[4], bfr[4];
#pragma unroll
      for (int m = 0; m < 4; ++m) {
        int r = wr * 64 + m * 16 + lr;
        int off = r * 128 + (((kk * 64) + (lg * 16)) ^ ((r & 7) << 4));
        af[m] = *(const bf16x8*)((const char*)&Al[cur][0] + off);
      }
#pragma unroll
      for (int n = 0; n < 4; ++n) {
        int r = wc * 64 + n * 16 + lr;
        int off = r * 128 + (((kk * 64) + (lg * 16)) ^ ((r & 7) << 4));
        bfr[n] = *(const bf16x8*)((const char*)&Bl[cur][0] + off);
      }
#pragma unroll
      for (int m = 0; m < 4; ++m)
#pragma unroll
        for (int n = 0; n < 4; ++n)
          acc[m][n] = __builtin_amdgcn_mfma_f32_16x16x32_bf16(af[m], bfr[n], acc[m][n], 0, 0, 0);
    }
    if (t + 1 < KT) writeB(cur ^ 1, bv);
    __syncthreads();
  }

  // epilogue: rnorm, logits, label margin, per-(row, 64col) max & sumexp
  float rn[4];
#pragma unroll
  for (int n = 0; n < 4; ++n) {
    float ssn = rowsum[wc * 64 + n * 16 + lr];
    rn[n] = 1.0f / fmaxf(sqrtf(ssn), 1e-12f);
  }
  int chunk2 = cchunk * 2 + wc;
#pragma unroll
  for (int m = 0; m < 4; ++m) {
#pragma unroll
    for (int i = 0; i < 4; ++i) {
      int rloc = wr * 64 + m * 16 + lg * 4 + i;   // C layout: row=4*(lane>>4)+reg
      int rglob = row0 + rloc;
      int lbl = lab[rloc];
      float lv[4];
      float lmax = NEG_BIG;
#pragma unroll
      for (int n = 0; n < 4; ++n) {
        int cg = c0 + wc * 64 + n * 16 + lr;       // C layout: col=lane&15
        float cosv = acc[m][n][i] * rn[n];
        float logit = kSCALE * cosv;
        if (cg == lbl) {
          float cc = fminf(fmaxf(cosv, -1.0f), 1.0f);
          float sine = sqrtf(fmaxf(1.0f - cc * cc, 0.0f));
          float phi = (cosv > kTHR) ? (cosv * kCOS_M - sine * kSIN_M)
                                    : (cosv - kMM);
          logit = kSCALE * phi;
          lablog[rglob] = logit;
        }
        if (cg >= NCLS) logit = NEG_BIG;           // padded classes
        lv[n] = logit;
        lmax = fmaxf(lmax, logit);
      }
      lmax = fmaxf(lmax, __shfl_xor(lmax, 1));
      lmax = fmaxf(lmax, __shfl_xor(lmax, 2));
      lmax = fmaxf(lmax, __shfl_xor(lmax, 4));
      lmax = fmaxf(lmax, __shfl_xor(lmax, 8));
      float ls = 0.f;
#pragma unroll
      for (int n = 0; n < 4; ++n) ls += __expf(lv[n] - lmax);
      ls += __shfl_xor(ls, 1); ls += __shfl_xor(ls, 2);
      ls += __shfl_xor(ls, 4); ls += __shfl_xor(ls, 8);
      if (lr == 0) {
        pmax[rglob * NCHUNK2 + chunk2] = lmax;
        psum[rglob * NCHUNK2 + chunk2] = ls;
      }
    }
  }
}

// ---------------- K3: combine partials -> per-row NLL ----------------
__global__ void kcombine(const float* __restrict__ pmax, const float* __restrict__ psum,
                         const float* __restrict__ lablog, float* __restrict__ nll)
{
  int b = blockIdx.x, tid = threadIdx.x;  // 256 threads
  float m = NEG_BIG, s = 0.f;
  for (int j = tid; j < NCHUNK2; j += 256) {
    float mj = pmax[b * NCHUNK2 + j];
    float sj = psum[b * NCHUNK2 + j];
    float M = fmaxf(m, mj);
    s = s * __expf(m - M) + sj * __expf(mj - M);
    m = M;
  }
#pragma unroll
  for (int d = 1; d < 64; d <<= 1) {
    float m2 = __shfl_xor(m, d);
    float s2 = __shfl_xor(s, d);
    float M = fmaxf(m, m2);
    s = s * __expf(m - M) + s2 * __expf(m2 - M);
    m = M;
  }
  __shared__ float sm[4], ssh[4];
  if ((tid & 63) == 0) { sm[tid >> 6] = m; ssh[tid >> 6] = s; }
  __syncthreads();
  if (tid == 0) {
    float M = sm[0], S = ssh[0];
    for (int k = 1; k < 4; ++k) {
      float Mn = fmaxf(M, sm[k]);
      S = S * __expf(M - Mn) + ssh[k] * __expf(sm[k] - Mn);
      M = Mn;
    }
    nll[b] = M + __logf(S) - lablog[b];
  }
}

// ---------------- K4: mean ----------------
__global__ void kmean(const float* __restrict__ nll, float* __restrict__ out) {
  int tid = threadIdx.x;  // 512
  float v = nll[tid];
#pragma unroll
  for (int d = 1; d < 64; d <<= 1) v += __shfl_xor(v, d);
  __shared__ float sm[8];
  if ((tid & 63) == 0) sm[tid >> 6] = v;
  __syncthreads();
  if (tid == 0) {
    float t = 0.f;
    for (int k = 0; k < 8; ++k) t += sm[k];
    out[0] = t * (1.0f / 512.0f);
  }
}

extern "C" void kernel_launch(void* const* d_in, const int* in_sizes, int n_in,
                              void* d_out, int out_size, void* d_ws, size_t ws_size,
                              hipStream_t stream)
{
  const float* E      = (const float*)d_in[0];
  const int*   labels = (const int*)d_in[1];
  const float* W      = (const float*)d_in[2];
  float* out = (float*)d_out;

  char* ws = (char*)d_ws;
  unsigned short* En = (unsigned short*)ws;                       // 512*512*2 = 524288 B
  float* pmax   = (float*)(ws + 524288);                          // 512*1564*4 = 3203072 B
  float* psum   = (float*)(ws + 524288 + 3203072);                // 3203072 B
  float* lablog = (float*)(ws + 524288 + 2 * 3203072);            // 2048 B
  float* nll    = lablog + BATCH;                                 // 2048 B

  knorm_e <<<BATCH, 64, 0, stream>>>(E, En);
  kgemm   <<<4 * NCHUNK, 256, 0, stream>>>(En, W, labels, pmax, psum, lablog);
  kcombine<<<BATCH, 256, 0, stream>>>(pmax, psum, lablog, nll);
  kmean   <<<1, BATCH, 0, stream>>>(nll, out);
}